// Round 1
// baseline (283.863 us; speedup 1.0000x reference)
//
#include <hip/hip_runtime.h>

#define T_STEPS 512
#define BATCH   2048
#define HID     64
#define IN0     8
#define SPW     16                // distinct seqs per block (MFMA N dim)
#define NBLK    (BATCH / SPW)     // 128 blocks x 4 waves (256 thr)
#define SS      8                 // x-prefetch depth
#define NSS     (T_STEPS / SS)

typedef _Float16 h2 __attribute__((ext_vector_type(2)));
typedef _Float16 h4 __attribute__((ext_vector_type(4)));
typedef _Float16 h8 __attribute__((ext_vector_type(8)));
typedef float    f4 __attribute__((ext_vector_type(4)));

#define MFMA(a, b, c) __builtin_amdgcn_mfma_f32_16x16x32_f16((a), (b), (c), 0, 0, 0)

union F8 { h8 v; h2 p[4]; };
union H4U { h4 v; h2 p[2]; };

__device__ __forceinline__ h2 pkrtz(float a, float b) {
    return __builtin_bit_cast(h2, __builtin_amdgcn_cvt_pkrtz(a, b));
}

// tanh(x) = 1 - 2/(exp(2x)+1); saturates correctly at +/-inf.
__device__ __forceinline__ float tanh_fast(float x) {
    float e = __builtin_amdgcn_exp2f(x * 2.885390081777927f);
    return 1.0f - 2.0f * __builtin_amdgcn_rcpf(e + 1.0f);
}

__device__ __forceinline__ h8 load_frag_f16(const float* Wrow) {
    const float4* p = (const float4*)Wrow;
    float4 a = p[0], b = p[1];
    F8 f; f.p[0] = pkrtz(a.x, a.y); f.p[1] = pkrtz(a.z, a.w);
          f.p[2] = pkrtz(b.x, b.y); f.p[3] = pkrtz(b.z, b.w);
    return f.v;
}

// Block barrier draining ONLY lgkmcnt (LDS). Unlike __syncthreads, this does
// NOT drain vmcnt — the x-prefetch global loads stay in flight across steps.
// lgkmcnt(0) covers both this step's LDS publishes and the previous step's
// LDS reads, so the 2-deep double-buffer stays race-free with one barrier/step.
#define LDS_BARRIER() asm volatile("s_waitcnt lgkmcnt(0)\n\ts_barrier" ::: "memory")

__global__ __launch_bounds__(256, 1)
void rnn2_merged(const float* __restrict__ x,
                 const float* __restrict__ Wih0, const float* __restrict__ Whh0,
                 const float* __restrict__ bih0, const float* __restrict__ bhh0,
                 const float* __restrict__ Wih1, const float* __restrict__ Whh1,
                 const float* __restrict__ bih1, const float* __restrict__ bhh1,
                 const float* __restrict__ fcw,  const float* __restrict__ fcb,
                 float* __restrict__ out) {
    const int tid  = threadIdx.x;
    const int mt   = tid >> 6;     // wave = m-tile (H rows 16mt..16mt+15), both layers
    const int lane = tid & 63;
    const int n    = lane & 15;    // B/C column = sequence (16 distinct)
    const int q    = lane >> 4;
    const int bseq = blockIdx.x * SPW;

    // H buffers [n][k], k-stride 72 (+8 pad, 0 conflicts verified previously);
    // double-buffered by t&1. Iteration t publishes H0(t), H1(t-1).
    __shared__ __align__(16) _Float16 H0b[2][SPW * 72];
    __shared__ __align__(16) _Float16 H1b[2][SPW * 72];
    __shared__ float red[4][SPW];

    const int widx  = n * 72 + mt * 16 + q * 4;   // this wave's C rows: k=16mt+4q+r
    const int ridx0 = n * 72 + 0 * 32 + q * 8;    // B-frag slices
    const int ridx1 = n * 72 + 1 * 32 + q * 8;

    const f4 zero = {0.f, 0.f, 0.f, 0.f};
    const h2 z2 = pkrtz(0.f, 0.f);

    // ---- per-wave weight fragments for BOTH layers (slot j <-> k = 32kt+8q+j) ----
    h8 wa0[2], wi0;                // layer0: Whh0, Wih0
    h8 wa1[2], wb1[2];             // layer1: Wih1, Whh1
    f4 biasc0, biasc1, fcv;
    const int row = 16 * mt + n;
    #pragma unroll
    for (int kt = 0; kt < 2; ++kt) {
        wa0[kt] = load_frag_f16(Whh0 + row * HID + 32 * kt + 8 * q);
        wa1[kt] = load_frag_f16(Wih1 + row * HID + 32 * kt + 8 * q);
        wb1[kt] = load_frag_f16(Whh1 + row * HID + 32 * kt + 8 * q);
    }
    {
        const float2 ww = *(const float2*)(Wih0 + row * IN0 + 2 * q);
        F8 f; f.p[0] = pkrtz(ww.x, ww.y); f.p[1] = z2; f.p[2] = z2; f.p[3] = z2;
        wi0 = f.v;
    }
    #pragma unroll
    for (int r = 0; r < 4; ++r) {
        const int i = 16 * mt + 4 * q + r;
        biasc0[r] = bih0[i] + bhh0[i];
        biasc1[r] = bih1[i] + bhh1[i];
        fcv[r]    = fcw[i];
    }
    const float fcb0 = fcb[0];

    const float* xrow = x + ((size_t)(bseq + n) * T_STEPS) * IN0 + 2 * q;

    h8 h0f[2] = {}, h1f[2] = {};   // H0(t-1); H1(t-2)
    f4 a0x;                        // bias0 + Wih0@x(t), computed one step ahead
    {
        const float2 x0 = *(const float2*)xrow;
        F8 xf; xf.p[0] = pkrtz(x0.x, x0.y); xf.p[1] = z2; xf.p[2] = z2; xf.p[3] = z2;
        a0x = MFMA(wi0, xf.v, biasc0);
    }

    for (int s = 0; s < NSS; ++s) {
        float2 xb[SS];
        #pragma unroll
        for (int i = 0; i < SS; ++i) {
            int tn = SS * s + i + 1; if (tn > T_STEPS - 1) tn = T_STEPS - 1;
            xb[i] = *(const float2*)(xrow + tn * IN0);
        }
        #pragma unroll
        for (int i = 0; i < SS; ++i) {
            const int t = SS * s + i;
            const int bf = t & 1;

            // Independent accumulators: both K-halves issue back-to-back,
            // chain = 1 MFMA latency + 1 VALU add (was 2 chained MFMAs).
            // L0: H0(t) = tanh(a0x + Whh0@H0(t-1))
            f4 p0 = MFMA(wa0[0], h0f[0], a0x);
            f4 p1 = MFMA(wa0[1], h0f[1], zero);
            // L1: H1(t-1) = tanh(b1 + Wih1@H0(t-1) + Whh1@H1(t-2))
            f4 q0 = MFMA(wa1[0], h0f[0], biasc1);
            f4 q1 = MFMA(wa1[1], h0f[1], zero);
            f4 q2 = MFMA(wb1[0], h1f[0], zero);
            f4 q3 = MFMA(wb1[1], h1f[1], zero);

            f4 a0 = p0 + p1;
            H4U u0;
            u0.p[0] = pkrtz(tanh_fast(a0[0]), tanh_fast(a0[1]));
            u0.p[1] = pkrtz(tanh_fast(a0[2]), tanh_fast(a0[3]));
            *(h4*)&H0b[bf][widx] = u0.v;

            f4 a1 = (q0 + q1) + (q2 + q3);
            H4U u1;
            u1.p[0] = pkrtz(tanh_fast(a1[0]), tanh_fast(a1[1]));
            u1.p[1] = pkrtz(tanh_fast(a1[2]), tanh_fast(a1[3]));
            if (t == 0) { u1.p[0] = z2; u1.p[1] = z2; }   // true H1(-1)=0
            *(h4*)&H1b[bf][widx] = u1.v;

            // a0x(t+1) — off the recurrence chain
            F8 xf; xf.p[0] = pkrtz(xb[i].x, xb[i].y);
            xf.p[1] = z2; xf.p[2] = z2; xf.p[3] = z2;
            a0x = MFMA(wi0, xf.v, biasc0);

            LDS_BARRIER();
            h0f[0] = *(const h8*)&H0b[bf][ridx0];
            h0f[1] = *(const h8*)&H0b[bf][ridx1];
            h1f[0] = *(const h8*)&H1b[bf][ridx0];
            h1f[1] = *(const h8*)&H1b[bf][ridx1];
        }
    }

    // ---- epilogue: H1(511) from h0f=H0(511), h1f=H1(510); FC head ----
    {
        f4 q0 = MFMA(wa1[0], h0f[0], biasc1);
        f4 q1 = MFMA(wa1[1], h0f[1], zero);
        f4 q2 = MFMA(wb1[0], h1f[0], zero);
        f4 q3 = MFMA(wb1[1], h1f[1], zero);
        const f4 a1 = (q0 + q1) + (q2 + q3);
        float sacc = 0.f;
        #pragma unroll
        for (int r = 0; r < 4; ++r) sacc += fcv[r] * tanh_fast(a1[r]);
        sacc += __shfl_xor(sacc, 16, 64);
        sacc += __shfl_xor(sacc, 32, 64);
        if (lane < 16) red[mt][n] = sacc;    // q==0 lanes
    }
    __syncthreads();
    if (tid < SPW)
        out[bseq + tid] = red[0][tid] + red[1][tid] + red[2][tid] + red[3][tid] + fcb0;
}

extern "C" void kernel_launch(void* const* d_in, const int* in_sizes, int n_in,
                              void* d_out, int out_size, void* d_ws, size_t ws_size,
                              hipStream_t stream) {
    const float* x    = (const float*)d_in[0];
    const float* Wih0 = (const float*)d_in[1];
    const float* Whh0 = (const float*)d_in[2];
    const float* bih0 = (const float*)d_in[3];
    const float* bhh0 = (const float*)d_in[4];
    const float* Wih1 = (const float*)d_in[5];
    const float* Whh1 = (const float*)d_in[6];
    const float* bih1 = (const float*)d_in[7];
    const float* bhh1 = (const float*)d_in[8];
    const float* fcw  = (const float*)d_in[9];
    const float* fcb  = (const float*)d_in[10];
    float* out = (float*)d_out;

    rnn2_merged<<<dim3(NBLK), dim3(256), 0, stream>>>(
        x, Wih0, Whh0, bih0, bhh0, Wih1, Whh1, bih1, bhh1, fcw, fcb, out);
}

// Round 2
// 272.680 us; speedup vs baseline: 1.0410x; 1.0410x over previous
//
#include <hip/hip_runtime.h>

#define T_STEPS 512
#define BATCH   2048
#define HID     64
#define IN0     8
#define SPW     16                // distinct seqs per block (MFMA N dim)
#define NBLK    (BATCH / SPW)     // 128 blocks x 8 waves (512 thr)
#define SS      8                 // x-prefetch depth
#define NSS     (T_STEPS / SS)

typedef _Float16 h2 __attribute__((ext_vector_type(2)));
typedef _Float16 h4 __attribute__((ext_vector_type(4)));
typedef _Float16 h8 __attribute__((ext_vector_type(8)));
typedef float    f4 __attribute__((ext_vector_type(4)));

#define MFMA(a, b, c) __builtin_amdgcn_mfma_f32_16x16x32_f16((a), (b), (c), 0, 0, 0)

union F8 { h8 v; h2 p[4]; };
union H4U { h4 v; h2 p[2]; };

__device__ __forceinline__ h2 pkrtz(float a, float b) {
    return __builtin_bit_cast(h2, __builtin_amdgcn_cvt_pkrtz(a, b));
}

// tanh(x) = 1 - 2/(exp(2x)+1); saturates correctly at +/-inf.
__device__ __forceinline__ float tanh_fast(float x) {
    float e = __builtin_amdgcn_exp2f(x * 2.885390081777927f);
    return 1.0f - 2.0f * __builtin_amdgcn_rcpf(e + 1.0f);
}

__device__ __forceinline__ h8 load_frag_f16(const float* Wrow) {
    const float4* p = (const float4*)Wrow;
    float4 a = p[0], b = p[1];
    F8 f; f.p[0] = pkrtz(a.x, a.y); f.p[1] = pkrtz(a.z, a.w);
          f.p[2] = pkrtz(b.x, b.y); f.p[3] = pkrtz(b.z, b.w);
    return f.v;
}

// Block barrier draining ONLY lgkmcnt (LDS). Unlike __syncthreads, this does
// NOT drain vmcnt — the x-prefetch global loads stay in flight across steps.
// lgkmcnt(0) covers this step's LDS publishes AND the previous step's LDS
// reads, so the 2-deep double-buffer stays race-free with one barrier/step.
#define LDS_BARRIER() asm volatile("s_waitcnt lgkmcnt(0)\n\ts_barrier" ::: "memory")

__global__ __launch_bounds__(512, 1)
void rnn2_split(const float* __restrict__ x,
                const float* __restrict__ Wih0, const float* __restrict__ Whh0,
                const float* __restrict__ bih0, const float* __restrict__ bhh0,
                const float* __restrict__ Wih1, const float* __restrict__ Whh1,
                const float* __restrict__ bih1, const float* __restrict__ bhh1,
                const float* __restrict__ fcw,  const float* __restrict__ fcb,
                float* __restrict__ out) {
    const int tid  = threadIdx.x;
    const int w    = tid >> 6;
    const int mt   = w & 3;        // m-tile (H rows 16mt..16mt+15)
    const bool L0  = (w < 4);      // waves 0-3: layer0; waves 4-7: layer1
    const int lane = tid & 63;
    const int n    = lane & 15;    // B/C column = sequence (16 distinct)
    const int q    = lane >> 4;
    const int bseq = blockIdx.x * SPW;

    // H buffers [n][k], k-stride 72 (+8 pad); double-buffered by t&1.
    // Iteration t publishes H0(t), H1(t-1).
    __shared__ __align__(16) _Float16 H0b[2][SPW * 72];
    __shared__ __align__(16) _Float16 H1b[2][SPW * 72];
    __shared__ float red[4][SPW];

    const int widx  = n * 72 + mt * 16 + q * 4;   // this wave's C rows: k=16mt+4q+r
    const int ridx0 = n * 72 + 0 * 32 + q * 8;    // B-frag slices
    const int ridx1 = n * 72 + 1 * 32 + q * 8;

    const f4 zero = {0.f, 0.f, 0.f, 0.f};
    const h2 z2 = pkrtz(0.f, 0.f);

    // ---- per-role weight fragments (slot j <-> k = 32kt+8q+j) ----
    h8 wa[2], wb[2], wi0;          // L0: wa=Whh0 | L1: wa=Wih1, wb=Whh1
    f4 biasc, fcv;
    const int row = 16 * mt + n;
    if (L0) {
        #pragma unroll
        for (int kt = 0; kt < 2; ++kt)
            wa[kt] = load_frag_f16(Whh0 + row * HID + 32 * kt + 8 * q);
        const float2 ww = *(const float2*)(Wih0 + row * IN0 + 2 * q);
        F8 f; f.p[0] = pkrtz(ww.x, ww.y); f.p[1] = z2; f.p[2] = z2; f.p[3] = z2;
        wi0 = f.v;
        #pragma unroll
        for (int r = 0; r < 4; ++r) {
            const int i = 16 * mt + 4 * q + r;
            biasc[r] = bih0[i] + bhh0[i];
        }
    } else {
        #pragma unroll
        for (int kt = 0; kt < 2; ++kt) {
            wa[kt] = load_frag_f16(Wih1 + row * HID + 32 * kt + 8 * q);
            wb[kt] = load_frag_f16(Whh1 + row * HID + 32 * kt + 8 * q);
        }
        #pragma unroll
        for (int r = 0; r < 4; ++r) {
            const int i = 16 * mt + 4 * q + r;
            biasc[r] = bih1[i] + bhh1[i];
            fcv[r]   = fcw[i];
        }
    }
    const float fcb0 = fcb[0];

    const float* xrow = x + ((size_t)(bseq + n) * T_STEPS) * IN0 + 2 * q;

    h8 h0f[2] = {}, h1f[2] = {};   // H0(t-1); (L1 only) H1(t-2)
    f4 a0x;                        // L0: bias0 + Wih0@x(t), one step ahead
    float2 xb_cur[SS], xb_nxt[SS]; // group-ahead x prefetch (L0 only)
    if (L0) {
        const float2 x0 = *(const float2*)xrow;
        F8 xf; xf.p[0] = pkrtz(x0.x, x0.y); xf.p[1] = z2; xf.p[2] = z2; xf.p[3] = z2;
        a0x = MFMA(wi0, xf.v, biasc);
        #pragma unroll
        for (int i = 0; i < SS; ++i) {
            int tn = i + 1; if (tn > T_STEPS - 1) tn = T_STEPS - 1;
            xb_cur[i] = *(const float2*)(xrow + tn * IN0);
        }
    }

    for (int s = 0; s < NSS; ++s) {
        if (L0) {
            // issue NEXT group's x loads now; they have 8 steps to land,
            // and no barrier in this loop drains vmcnt.
            #pragma unroll
            for (int i = 0; i < SS; ++i) {
                int tn = SS * (s + 1) + i + 1; if (tn > T_STEPS - 1) tn = T_STEPS - 1;
                xb_nxt[i] = *(const float2*)(xrow + tn * IN0);
            }
        }
        #pragma unroll
        for (int i = 0; i < SS; ++i) {
            const int t = SS * s + i;
            const int bf = t & 1;
            if (L0) {
                // H0(t) = tanh(a0x + Whh0@H0(t-1)); independent accumulators
                f4 p0 = MFMA(wa[0], h0f[0], a0x);
                f4 p1 = MFMA(wa[1], h0f[1], zero);
                const f4 a0 = p0 + p1;
                H4U u;
                u.p[0] = pkrtz(tanh_fast(a0[0]), tanh_fast(a0[1]));
                u.p[1] = pkrtz(tanh_fast(a0[2]), tanh_fast(a0[3]));
                *(h4*)&H0b[bf][widx] = u.v;
                // a0x(t+1) — off the chain
                F8 xf; xf.p[0] = pkrtz(xb_cur[i].x, xb_cur[i].y);
                xf.p[1] = z2; xf.p[2] = z2; xf.p[3] = z2;
                a0x = MFMA(wi0, xf.v, biasc);
            } else {
                // H1(t-1) = tanh(b1 + Wih1@H0(t-1) + Whh1@H1(t-2))
                f4 c0 = MFMA(wa[0], h0f[0], biasc);
                f4 c1 = MFMA(wa[1], h0f[1], zero);
                f4 c2 = MFMA(wb[0], h1f[0], zero);
                f4 c3 = MFMA(wb[1], h1f[1], zero);
                const f4 a1 = (c0 + c1) + (c2 + c3);
                H4U u;
                u.p[0] = pkrtz(tanh_fast(a1[0]), tanh_fast(a1[1]));
                u.p[1] = pkrtz(tanh_fast(a1[2]), tanh_fast(a1[3]));
                if (t == 0) { u.p[0] = z2; u.p[1] = z2; }   // true H1(-1)=0
                *(h4*)&H1b[bf][widx] = u.v;
            }
            LDS_BARRIER();
            h0f[0] = *(const h8*)&H0b[bf][ridx0];
            h0f[1] = *(const h8*)&H0b[bf][ridx1];
            if (!L0) {
                h1f[0] = *(const h8*)&H1b[bf][ridx0];
                h1f[1] = *(const h8*)&H1b[bf][ridx1];
            }
        }
        if (L0) {
            #pragma unroll
            for (int i = 0; i < SS; ++i) xb_cur[i] = xb_nxt[i];
        }
    }

    // ---- epilogue: H1(511) from h0f=H0(511), h1f=H1(510); FC head ----
    if (!L0) {
        f4 c0 = MFMA(wa[0], h0f[0], biasc);
        f4 c1 = MFMA(wa[1], h0f[1], zero);
        f4 c2 = MFMA(wb[0], h1f[0], zero);
        f4 c3 = MFMA(wb[1], h1f[1], zero);
        const f4 a1 = (c0 + c1) + (c2 + c3);
        float sacc = 0.f;
        #pragma unroll
        for (int r = 0; r < 4; ++r) sacc += fcv[r] * tanh_fast(a1[r]);
        sacc += __shfl_xor(sacc, 16, 64);
        sacc += __shfl_xor(sacc, 32, 64);
        if (lane < 16) red[mt][n] = sacc;    // q==0 lanes
    }
    __syncthreads();
    if (tid < SPW)
        out[bseq + tid] = red[0][tid] + red[1][tid] + red[2][tid] + red[3][tid] + fcb0;
}

extern "C" void kernel_launch(void* const* d_in, const int* in_sizes, int n_in,
                              void* d_out, int out_size, void* d_ws, size_t ws_size,
                              hipStream_t stream) {
    const float* x    = (const float*)d_in[0];
    const float* Wih0 = (const float*)d_in[1];
    const float* Whh0 = (const float*)d_in[2];
    const float* bih0 = (const float*)d_in[3];
    const float* bhh0 = (const float*)d_in[4];
    const float* Wih1 = (const float*)d_in[5];
    const float* Whh1 = (const float*)d_in[6];
    const float* bih1 = (const float*)d_in[7];
    const float* bhh1 = (const float*)d_in[8];
    const float* fcw  = (const float*)d_in[9];
    const float* fcb  = (const float*)d_in[10];
    float* out = (float*)d_out;

    rnn2_split<<<dim3(NBLK), dim3(512), 0, stream>>>(
        x, Wih0, Whh0, bih0, bhh0, Wih1, Whh1, bih1, bhh1, fcw, fcb, out);
}